// Round 1
// baseline (1073.766 us; speedup 1.0000x reference)
//
#include <hip/hip_runtime.h>

// Problem constants
#define HH 768
#define WW 768
#define CIN 64
#define COUT 64
#define BOUT 48
#define NBLK 256

// ws layout (floats):
// [0, 36864)      wt[ci][kh][kw][c]   (576 * 64)
// [36864, 36928)  scale[c]
// [36928, 36992)  shift[c]
// [36992, 37504)  flags[512] (int)
#define WS_WT     0
#define WS_SCALE  36864
#define WS_SHIFT  36928
#define WS_FLAGS  36992

__global__ __launch_bounds__(256) void prep_kernel(
    const float* __restrict__ conv_w,
    const float* __restrict__ conv_b,
    const float* __restrict__ gamma,
    const float* __restrict__ beta,
    const float* __restrict__ run_mean,
    const float* __restrict__ run_var,
    const int* __restrict__ abi,
    float* __restrict__ ws) {
  int tid = threadIdx.x;
  float* wt = ws + WS_WT;
  float* scale = ws + WS_SCALE;
  float* shift = ws + WS_SHIFT;
  int* flags = (int*)(ws + WS_FLAGS);

  // zero flag table (512 entries), then mark actives
  flags[tid] = 0;
  flags[tid + 256] = 0;
  __syncthreads();
  {
    int n = abi[3 * tid + 0];
    int bh = abi[3 * tid + 1];
    int bw = abi[3 * tid + 2];
    flags[n * 256 + bh * 16 + bw] = 1;
  }

  // transpose conv_w (c, ci, kh, kw) -> wt (ci, kh, kw, c)
  for (int d = tid; d < 576 * 64; d += 256) {
    int c = d & 63;
    int r = d >> 6;           // r = ci*9 + kh*3 + kw
    int kw = r % 3;
    int t = r / 3;
    int kh = t % 3;
    int ci = t / 3;
    wt[d] = conv_w[(c * 64 + ci) * 9 + kh * 3 + kw];
  }

  // folded BN: out = relu(conv * scale[c] + shift[c])
  if (tid < 64) {
    float inv = gamma[tid] * rsqrtf(run_var[tid] + 1e-3f);
    scale[tid] = inv;
    shift[tid] = (conv_b[tid] - run_mean[tid]) * inv + beta[tid];
  }
}

__global__ __launch_bounds__(256) void zero_kernel(
    const float* __restrict__ ws, float* __restrict__ out) {
  const int* flags = (const int*)(ws + WS_FLAGS);
  int tile = blockIdx.x;
  if (flags[tile]) return;
  int n = tile >> 8;
  int bh = (tile >> 4) & 15;
  int bw = tile & 15;
  int h0 = bh * 48;
  int w0 = bw * 48;
  float4 z = make_float4(0.f, 0.f, 0.f, 0.f);
  // 64 channels * 48 rows * 12 float4 per row
  for (int idx = threadIdx.x; idx < 64 * 48 * 12; idx += 256) {
    int j4 = idx % 12;
    int rr = idx / 12;
    int i = rr % 48;
    int c = rr / 48;
    float4* p = (float4*)(out + ((c + n * 64) * 768 + (h0 + i)) * 768 + w0) + j4;
    *p = z;
  }
}

// grid: (9 subtiles, 256 active blocks); block: 256 threads (16x16 pixels)
__global__ __launch_bounds__(256) void conv_kernel(
    const float* __restrict__ x,
    const float* __restrict__ ws,
    const int* __restrict__ abi,
    float* __restrict__ out) {
  __shared__ float lds[16 * 324];  // 16 channels x (18x18) patch, 20.7 KB
  const float* wt = ws + WS_WT;
  const float* scale = ws + WS_SCALE;
  const float* shift = ws + WS_SHIFT;

  int b = blockIdx.y;
  int sub = blockIdx.x;
  int n = abi[3 * b + 0];
  int bh = abi[3 * b + 1];
  int bw = abi[3 * b + 2];
  int sy = (sub / 3) * 16;
  int sx = (sub % 3) * 16;
  int h0 = bh * 48 + sy;
  int w0 = bw * 48 + sx;

  int tid = threadIdx.x;
  int px = tid & 15;
  int py = tid >> 4;

  float acc[64];
#pragma unroll
  for (int c = 0; c < 64; ++c) acc[c] = 0.f;

  for (int cc = 0; cc < 4; ++cc) {
    __syncthreads();
    // stage 16 channels of the 18x18 input patch (zero-padded at borders)
    for (int e = tid; e < 16 * 324; e += 256) {
      int ci = e / 324;
      int rem = e - ci * 324;
      int r = rem / 18;
      int col = rem - r * 18;
      int gh = h0 - 1 + r;
      int gw = w0 - 1 + col;
      float v = 0.f;
      if ((unsigned)gh < 768u && (unsigned)gw < 768u)
        v = x[((n * 64 + cc * 16 + ci) * 768 + gh) * 768 + gw];
      lds[e] = v;
    }
    __syncthreads();

    for (int ci = 0; ci < 16; ++ci) {
      const float* lp = lds + ci * 324 + py * 18 + px;
      float v[9];
      v[0] = lp[0];  v[1] = lp[1];  v[2] = lp[2];
      v[3] = lp[18]; v[4] = lp[19]; v[5] = lp[20];
      v[6] = lp[36]; v[7] = lp[37]; v[8] = lp[38];
      const float* wp = wt + (cc * 16 + ci) * 576;  // uniform -> s_load
#pragma unroll
      for (int k = 0; k < 9; ++k) {
#pragma unroll
        for (int c = 0; c < 64; ++c) {
          acc[c] = fmaf(v[k], wp[k * 64 + c], acc[c]);
        }
      }
    }
  }

  // epilogue: folded BN + ReLU, store
  int h = h0 + py;
  int w = w0 + px;
#pragma unroll
  for (int c = 0; c < 64; ++c) {
    float vv = fmaf(acc[c], scale[c], shift[c]);
    out[((n * 64 + c) * 768 + h) * 768 + w] = vv > 0.f ? vv : 0.f;
  }
}

extern "C" void kernel_launch(void* const* d_in, const int* in_sizes, int n_in,
                              void* d_out, int out_size, void* d_ws, size_t ws_size,
                              hipStream_t stream) {
  const float* x = (const float*)d_in[0];
  const float* conv_w = (const float*)d_in[1];
  const float* conv_b = (const float*)d_in[2];
  const float* gamma = (const float*)d_in[3];
  const float* beta = (const float*)d_in[4];
  const float* run_mean = (const float*)d_in[5];
  const float* run_var = (const float*)d_in[6];
  const int* abi = (const int*)d_in[7];
  float* out = (float*)d_out;
  float* ws = (float*)d_ws;

  prep_kernel<<<1, 256, 0, stream>>>(conv_w, conv_b, gamma, beta,
                                     run_mean, run_var, abi, ws);
  zero_kernel<<<512, 256, 0, stream>>>(ws, out);
  conv_kernel<<<dim3(9, 256), 256, 0, stream>>>(x, ws, abi, out);
}

// Round 2
// 691.752 us; speedup vs baseline: 1.5522x; 1.5522x over previous
//
#include <hip/hip_runtime.h>

// Problem constants: N=2, CIN=COUT=64, H=W=768, K=3, pad=1, 256 active 48x48 blocks

typedef __attribute__((ext_vector_type(8))) short short8;
typedef __attribute__((ext_vector_type(4))) float floatx4;

// ws layout (float slots):
// [0,64)    scale
// [64,128)  shift
// [128,640) flags (512 ints)
// [640,...) wb: 36864 bf16 weights, layout [step=s*2+h][cout][k32]
#define WS_SCALE 0
#define WS_SHIFT 64
#define WS_FLAGS 128
#define WS_WB    640

__device__ __forceinline__ short f2bf(float f) {
  unsigned u = __builtin_bit_cast(unsigned, f);
  u += 0x7fffu + ((u >> 16) & 1u);
  return (short)(u >> 16);
}

__global__ __launch_bounds__(256) void prep_kernel(
    const float* __restrict__ conv_w,
    const float* __restrict__ conv_b,
    const float* __restrict__ gamma,
    const float* __restrict__ beta,
    const float* __restrict__ run_mean,
    const float* __restrict__ run_var,
    const int* __restrict__ abi,
    float* __restrict__ ws) {
  int tid = threadIdx.x;
  if (blockIdx.x == 0) {
    int* flags = (int*)(ws + WS_FLAGS);
    flags[tid] = 0;
    flags[tid + 256] = 0;
    __syncthreads();
    int n = abi[3 * tid + 0];
    int bh = abi[3 * tid + 1];
    int bw = abi[3 * tid + 2];
    flags[n * 256 + bh * 16 + bw] = 1;
    if (tid < 64) {
      float inv = gamma[tid] * rsqrtf(run_var[tid] + 1e-3f);
      ws[WS_SCALE + tid] = inv;
      ws[WS_SHIFT + tid] = (conv_b[tid] - run_mean[tid]) * inv + beta[tid];
    }
  }
  // weight repack: wb[((s*2+h)*64 + cout)*32 + k] = bf16(conv_w[cout][h*32+k][dy][dx])
  short* wb = (short*)(ws + WS_WB);
  int gt = blockIdx.x * 256 + tid;
  for (int d = gt; d < 36864; d += 64 * 256) {
    int k = d & 31;
    int n2 = (d >> 5) & 63;
    int step = d >> 11;        // 0..17
    int h = step & 1;
    int s = step >> 1;         // 0..8
    int dy = s / 3;
    int dx = s - dy * 3;
    int ci = h * 32 + k;
    wb[d] = f2bf(conv_w[((n2 * 64 + ci) * 3 + dy) * 3 + dx]);
  }
}

__global__ __launch_bounds__(256) void zero_kernel(
    const float* __restrict__ ws, float* __restrict__ out) {
  const int* flags = (const int*)(ws + WS_FLAGS);
  int tile = blockIdx.x;
  if (flags[tile]) return;
  int n = tile >> 8;
  int bh = (tile >> 4) & 15;
  int bw = tile & 15;
  int h0 = bh * 48;
  int w0 = bw * 48;
  float4 z = make_float4(0.f, 0.f, 0.f, 0.f);
  for (int idx = threadIdx.x; idx < 64 * 48 * 12; idx += 256) {
    int j4 = idx % 12;
    int rr = idx / 12;
    int i = rr % 48;
    int c = rr / 48;
    float4* p = (float4*)(out + ((c + n * 64) * 768 + (h0 + i)) * 768 + w0) + j4;
    *p = z;
  }
}

// grid (9 subtiles, 256 active blocks), 256 threads = 4 waves.
// GEMM: M=cout(64) x N=pixel(256) x K=576. Wave w handles output rows 4w..4w+3.
__global__ __launch_bounds__(256, 3) void conv_kernel(
    const float* __restrict__ x,
    const float* __restrict__ ws,
    const int* __restrict__ abi,
    float* __restrict__ out) {
  // patch LDS: [plane=ci>>3][r][c][ci&7] bf16, plane stride 2592 shorts (5184 B)
  __shared__ short8 lds8[8 * 324];
  short* lds = (short*)lds8;

  int b = blockIdx.y;
  int sub = blockIdx.x;
  int n = abi[3 * b + 0];
  int bh = abi[3 * b + 1];
  int bw = abi[3 * b + 2];
  int h0 = bh * 48 + (sub / 3) * 16;
  int w0 = bw * 48 + (sub % 3) * 16;
  int tid = threadIdx.x;

  // ---- stage 18x18x64 input patch, fp32 -> bf16 ----
  const float* xn = x + n * 64 * 768 * 768;
#pragma unroll 3
  for (int i = 0; i < 81; ++i) {
    int e = tid + i * 256;
    int ci = e / 324;
    int rem = e - ci * 324;
    int r = rem / 18;
    int c = rem - r * 18;
    int gh = h0 - 1 + r;
    int gw = w0 - 1 + c;
    float v = 0.f;
    if ((unsigned)gh < 768u && (unsigned)gw < 768u)
      v = xn[(ci * 768 + gh) * 768 + gw];
    lds[(ci >> 3) * 2592 + (r * 18 + c) * 8 + (ci & 7)] = f2bf(v);
  }
  __syncthreads();

  int lane = tid & 63;
  int wv = tid >> 6;           // wave id 0..3 -> output rows 4wv..4wv+3
  int ln15 = lane & 15;        // pixel col (B/N index) / cout low (A/M index)
  int quad = lane >> 4;

  // B-frag (pixels) base: plane=quad (+4h), pixel (row=4wv(+t+dy), col=ln15(+dx))
  const short* lp = lds + quad * 2592 + (4 * wv * 18 + ln15) * 8;
  // A-frag (weights) base
  const short* wbp = (const short*)(ws + WS_WB) + ln15 * 32 + quad * 8;

  floatx4 acc[4][4];  // [t=row][mf=cout group]
#pragma unroll
  for (int t = 0; t < 4; ++t)
#pragma unroll
    for (int mf = 0; mf < 4; ++mf)
      acc[t][mf] = (floatx4){0.f, 0.f, 0.f, 0.f};

  for (int s = 0; s < 9; ++s) {      // spatial tap (dy,dx)
    int dy = s / 3;
    int dx = s - dy * 3;
    const short* lps = lp + (dy * 18 + dx) * 8;
    const short* wps = wbp + s * 4096;  // 2 steps * 2048 shorts
#pragma unroll
    for (int h = 0; h < 2; ++h) {       // channel chunk of 32
      short8 af[4];
#pragma unroll
      for (int mf = 0; mf < 4; ++mf)
        af[mf] = *(const short8*)(wps + h * 2048 + mf * 512);
#pragma unroll
      for (int t = 0; t < 4; ++t) {
        short8 bf = *(const short8*)(lps + h * 10368 + t * 144);
#pragma unroll
        for (int mf = 0; mf < 4; ++mf)
          acc[t][mf] = __builtin_amdgcn_mfma_f32_16x16x32_bf16(
              af[mf], bf, acc[t][mf], 0, 0, 0);
      }
    }
  }

  // ---- epilogue: BN fold + ReLU + store ----
  // D layout: row(M=cout) = quad*4+reg, col(N=pixel) = ln15
  const float* scale = ws + WS_SCALE;
  const float* shift = ws + WS_SHIFT;
  float* outn = out + n * 64 * 768 * 768;
#pragma unroll
  for (int mf = 0; mf < 4; ++mf) {
#pragma unroll
    for (int reg = 0; reg < 4; ++reg) {
      int cout = mf * 16 + quad * 4 + reg;
      float sc = scale[cout];
      float sh = shift[cout];
#pragma unroll
      for (int t = 0; t < 4; ++t) {
        float v = fmaf(acc[t][mf][reg], sc, sh);
        v = v > 0.f ? v : 0.f;
        outn[(cout * 768 + h0 + 4 * wv + t) * 768 + w0 + ln15] = v;
      }
    }
  }
}

extern "C" void kernel_launch(void* const* d_in, const int* in_sizes, int n_in,
                              void* d_out, int out_size, void* d_ws, size_t ws_size,
                              hipStream_t stream) {
  const float* x = (const float*)d_in[0];
  const float* conv_w = (const float*)d_in[1];
  const float* conv_b = (const float*)d_in[2];
  const float* gamma = (const float*)d_in[3];
  const float* beta = (const float*)d_in[4];
  const float* run_mean = (const float*)d_in[5];
  const float* run_var = (const float*)d_in[6];
  const int* abi = (const int*)d_in[7];
  float* out = (float*)d_out;
  float* ws = (float*)d_ws;

  prep_kernel<<<64, 256, 0, stream>>>(conv_w, conv_b, gamma, beta,
                                      run_mean, run_var, abi, ws);
  zero_kernel<<<512, 256, 0, stream>>>(ws, out);
  conv_kernel<<<dim3(9, 256), 256, 0, stream>>>(x, ws, abi, out);
}

// Round 3
// 582.172 us; speedup vs baseline: 1.8444x; 1.1882x over previous
//
#include <hip/hip_runtime.h>

// N=2, CIN=COUT=64, H=W=768, K=3, pad=1, 256 active 48x48 blocks.

typedef __attribute__((ext_vector_type(8))) short short8;
typedef __attribute__((ext_vector_type(4))) float floatx4;

// ws layout (float slots):
// [0,64)    scale
// [64,128)  shift
// [128,640) flags (512 ints)
// [640,..)  wa: 49152 bf16 A-frag weights: [ks=cc*3+kt][cout][quad(tap)][j(ci8)]
#define WS_SCALE 0
#define WS_SHIFT 64
#define WS_FLAGS 128
#define WS_WA    640

#define CONV_WGS 1536   // 256 blocks * 6 strips
#define ZERO_WGS 4096   // 512 tiles * 8 channel-parts

__device__ __forceinline__ short f2bf(float f) {
  unsigned u = __builtin_bit_cast(unsigned, f);
  u += 0x7fffu + ((u >> 16) & 1u);
  return (short)(u >> 16);
}

__global__ __launch_bounds__(256) void prep_kernel(
    const float* __restrict__ conv_w,
    const float* __restrict__ conv_b,
    const float* __restrict__ gamma,
    const float* __restrict__ beta,
    const float* __restrict__ run_mean,
    const float* __restrict__ run_var,
    const int* __restrict__ abi,
    float* __restrict__ ws) {
  int tid = threadIdx.x;
  if (blockIdx.x == 0) {
    int* flags = (int*)(ws + WS_FLAGS);
    flags[tid] = 0;
    flags[tid + 256] = 0;
    __syncthreads();
    int n = abi[3 * tid + 0];
    int bh = abi[3 * tid + 1];
    int bw = abi[3 * tid + 2];
    flags[n * 256 + bh * 16 + bw] = 1;
    if (tid < 64) {
      float inv = gamma[tid] * rsqrtf(run_var[tid] + 1e-3f);
      ws[WS_SCALE + tid] = inv;
      ws[WS_SHIFT + tid] = (conv_b[tid] - run_mean[tid]) * inv + beta[tid];
    }
  }
  // A-frag weight pack: wa[((ks*64 + cout)*4 + q)*8 + j]
  //   ks = cc*3+kt; tap = kt*4+q; element = w[cout][ci=cc*8+j][tap] or 0 (pad)
  short* wa = (short*)(ws + WS_WA);
  for (int d = blockIdx.x * 256 + tid; d < 49152; d += 64 * 256) {
    int j = d & 7;
    int q = (d >> 3) & 3;
    int cout = (d >> 5) & 63;
    int ks = d >> 11;          // 0..23
    int kt = ks % 3;
    int cc = ks / 3;
    int tap = kt * 4 + q;
    short v = 0;
    if (tap < 9) {
      int ci = cc * 8 + j;
      int dy = tap / 3;
      int dx = tap - dy * 3;
      v = f2bf(conv_w[((cout * 64 + ci) * 3 + dy) * 3 + dx]);
    }
    wa[d] = v;
  }
}

// Merged conv + zero kernel. 512 threads.
// conv wgs: blockIdx < CONV_WGS, one 48x8 output strip each.
// zero wgs: fill inactive tiles (8 channels per wg).
__global__ __launch_bounds__(512, 4) void main_kernel(
    const float* __restrict__ x,
    const float* __restrict__ ws_f,
    const int* __restrict__ abi,
    float* __restrict__ out) {
  __shared__ __align__(16) short lds[2][4008];  // [buf][(r*50+c)*8+ci], +8 zero pad
  int b = blockIdx.x;
  int tid = threadIdx.x;

  if (b >= CONV_WGS) {
    // ---- zero path: inactive tiles ----
    const int* flags = (const int*)(ws_f + WS_FLAGS);
    int z = b - CONV_WGS;
    int tile = z >> 3;
    int part = z & 7;
    if (flags[tile]) return;
    int n = tile >> 8;
    int bh = (tile >> 4) & 15;
    int bw = tile & 15;
    float* base = out + (((n * 64 + part * 8) * 768 + bh * 48)) * 768 + bw * 48;
    float4 zv = make_float4(0.f, 0.f, 0.f, 0.f);
#pragma unroll
    for (int i = 0; i < 9; ++i) {        // 8ch*48r*12f4 = 4608
      int idx = i * 512 + tid;
      int f = idx % 12;
      int t2 = idx / 12;
      int rr = t2 % 48;
      int c = t2 / 48;                    // 0..7
      *((float4*)(base + (c * 768 + rr) * (size_t)768) + f) = zv;
    }
    return;
  }

  // ---- conv path ----
  int blk = b / 6;
  int strip = b - blk * 6;
  int n = abi[3 * blk + 0];
  int bh = abi[3 * blk + 1];
  int bw = abi[3 * blk + 2];
  int h0 = bh * 48 + strip * 8;   // output rows h0..h0+7
  int w0 = bw * 48;

  int lane = tid & 63;
  int wv = tid >> 6;              // wave 0..7 -> output row h0+wv
  int ln15 = lane & 15;
  int quad = lane >> 4;

  const float* xn = x + (size_t)n * 64 * 768 * 768;
  const short* wa = (const short*)(ws_f + WS_WA);

  // zero-pad region for padded taps (same-address broadcast read)
  if (tid < 8) { lds[0][4000 + tid] = 0; lds[1][4000 + tid] = 0; }

  // per-lane B-frag byte addresses: bA[kt][c16]
  int bA[3][3];
#pragma unroll
  for (int kt = 0; kt < 3; ++kt) {
    int tap = kt * 4 + quad;
    if (tap < 9) {
      int dy = tap / 3;
      int dx = tap - dy * 3;
      int a0 = ((wv + dy) * 50 + ln15 + dx) * 16;
#pragma unroll
      for (int c16 = 0; c16 < 3; ++c16) bA[kt][c16] = a0 + c16 * 256;
    } else {
#pragma unroll
      for (int c16 = 0; c16 < 3; ++c16) bA[kt][c16] = 8000;  // zero region
    }
  }

  // stage decode: e -> (f:14, r:10, ci:8); gw window [w0-4, w0+52)
  auto load_chunk = [&](int cc8, float4* pf) {
#pragma unroll
    for (int i = 0; i < 3; ++i) {
      int e = i * 512 + tid;
      float4 v = make_float4(0.f, 0.f, 0.f, 0.f);
      if (e < 1120) {
        int f = e % 14;
        int t = e / 14;
        int r = t % 10;
        int ci = t / 10;
        int gh = h0 - 1 + r;
        int gw0 = w0 - 4 + 4 * f;
        if ((unsigned)gh < 768u) {
          const float* rp = xn + ((size_t)(cc8 + ci) * 768 + gh) * 768;
          if (gw0 >= 0 && gw0 <= 764) {
            v = *(const float4*)(rp + gw0);
          } else {
#pragma unroll
            for (int j = 0; j < 4; ++j) {
              int gw = gw0 + j;
              if ((unsigned)gw < 768u) ((float*)&v)[j] = rp[gw];
            }
          }
        }
      }
      pf[i] = v;
    }
  };
  auto store_chunk = [&](int bsel, const float4* pf) {
#pragma unroll
    for (int i = 0; i < 3; ++i) {
      int e = i * 512 + tid;
      if (e < 1120) {
        int f = e % 14;
        int t = e / 14;
        int r = t % 10;
        int ci = t / 10;
        const float* vp = (const float*)&pf[i];
#pragma unroll
        for (int j = 0; j < 4; ++j) {
          int c = 4 * f - 3 + j;
          if ((unsigned)c < 50u)
            lds[bsel][(r * 50 + c) * 8 + ci] = f2bf(vp[j]);
        }
      }
    }
  };

  float4 pf[3];
  // prologue: stage chunk 0 into buf 0
  load_chunk(0, pf);
  store_chunk(0, pf);
  __syncthreads();

  floatx4 acc[3][4];
#pragma unroll
  for (int c16 = 0; c16 < 3; ++c16)
#pragma unroll
    for (int mt = 0; mt < 4; ++mt)
      acc[c16][mt] = (floatx4){0.f, 0.f, 0.f, 0.f};

  for (int cc = 0; cc < 8; ++cc) {
    int bsel = cc & 1;
    if (cc < 7) load_chunk((cc + 1) * 8, pf);   // prefetch next chunk
    const char* lbase = (const char*)lds[bsel];
#pragma unroll
    for (int kt = 0; kt < 3; ++kt) {
      int ks = cc * 3 + kt;
      short8 af[4];
#pragma unroll
      for (int mt = 0; mt < 4; ++mt)
        af[mt] = *(const short8*)(wa + ks * 2048 + (mt * 16 + ln15) * 32 + quad * 8);
#pragma unroll
      for (int c16 = 0; c16 < 3; ++c16) {
        short8 bf = *(const short8*)(lbase + bA[kt][c16]);
#pragma unroll
        for (int mt = 0; mt < 4; ++mt)
          acc[c16][mt] = __builtin_amdgcn_mfma_f32_16x16x32_bf16(
              af[mt], bf, acc[c16][mt], 0, 0, 0);
      }
    }
    if (cc < 7) store_chunk(bsel ^ 1, pf);
    __syncthreads();
  }

  // ---- epilogue: BN fold + ReLU + store ----
  // D layout: row(m=cout within tile) = quad*4+reg, col(n=pixel) = ln15
  const float* scale = ws_f + WS_SCALE;
  const float* shift = ws_f + WS_SHIFT;
  float* outn = out + (size_t)n * 64 * 768 * 768;
  int gr = h0 + wv;
#pragma unroll
  for (int mt = 0; mt < 4; ++mt) {
#pragma unroll
    for (int reg = 0; reg < 4; ++reg) {
      int cout = mt * 16 + quad * 4 + reg;
      float sc = scale[cout];
      float sh = shift[cout];
#pragma unroll
      for (int c16 = 0; c16 < 3; ++c16) {
        float vv = fmaf(acc[c16][mt][reg], sc, sh);
        vv = vv > 0.f ? vv : 0.f;
        outn[((size_t)cout * 768 + gr) * 768 + w0 + c16 * 16 + ln15] = vv;
      }
    }
  }
}

extern "C" void kernel_launch(void* const* d_in, const int* in_sizes, int n_in,
                              void* d_out, int out_size, void* d_ws, size_t ws_size,
                              hipStream_t stream) {
  const float* x = (const float*)d_in[0];
  const float* conv_w = (const float*)d_in[1];
  const float* conv_b = (const float*)d_in[2];
  const float* gamma = (const float*)d_in[3];
  const float* beta = (const float*)d_in[4];
  const float* run_mean = (const float*)d_in[5];
  const float* run_var = (const float*)d_in[6];
  const int* abi = (const int*)d_in[7];
  float* out = (float*)d_out;
  float* ws = (float*)d_ws;

  prep_kernel<<<64, 256, 0, stream>>>(conv_w, conv_b, gamma, beta,
                                      run_mean, run_var, abi, ws);
  main_kernel<<<CONV_WGS + ZERO_WGS, 512, 0, stream>>>(x, ws, abi, out);
}